// Round 2
// baseline (1033.457 us; speedup 1.0000x reference)
//
#include <hip/hip_runtime.h>

__device__ __forceinline__ void cload(float* dst, const float* src, int n){
    for (int i = threadIdx.x; i < n; i += 256) dst[i] = src[i];
}
// scatter a (3, n) array into per-layer blocks of stride 1330 at offset `off`
__device__ __forceinline__ void cload3(float* TW, int off, const float* src, int n){
    for (int i = threadIdx.x; i < 3*n; i += 256){
        int L = i / n, j = i - L*n;
        TW[L*1330 + off + j] = src[i];
    }
}

__device__ __forceinline__ void ln10(const float* in, float* out, const float* g, const float* b){
    float m = 0.f;
#pragma unroll
    for (int c = 0; c < 10; ++c) m += in[c];
    m *= 0.1f;
    float v = 0.f;
#pragma unroll
    for (int c = 0; c < 10; ++c){ float d = in[c] - m; v += d*d; }
    v *= 0.1f;
    float inv = rsqrtf(v + 1e-5f);
#pragma unroll
    for (int c = 0; c < 10; ++c) out[c] = (in[c] - m) * inv * g[c] + b[c];
}

__global__ __launch_bounds__(256)
void featurer_kernel(
    const float* __restrict__ X,
    const float* __restrict__ CWg, const float* __restrict__ CBg,
    const float* __restrict__ PWg, const float* __restrict__ PBg,
    const float* __restrict__ PGg, const float* __restrict__ PBEg,
    const float* __restrict__ W1g, const float* __restrict__ B1g,
    const float* __restrict__ BNGg, const float* __restrict__ BNBg,
    const float* __restrict__ BNMg, const float* __restrict__ BNVg,
    const float* __restrict__ W2g, const float* __restrict__ B2g,
    const float* __restrict__ LN1Gg, const float* __restrict__ LN1Bg,
    const float* __restrict__ QWg, const float* __restrict__ QBg,
    const float* __restrict__ KWg, const float* __restrict__ KBg,
    const float* __restrict__ VWg, const float* __restrict__ VBg,
    const float* __restrict__ OWg, const float* __restrict__ OBg,
    const float* __restrict__ LN2Gg, const float* __restrict__ LN2Bg,
    const float* __restrict__ F1Wg, const float* __restrict__ F1Bg,
    const float* __restrict__ F2Wg, const float* __restrict__ F2Bg,
    float* __restrict__ OUT)
{
    // LDS: s_big holds h[16][1000] f32 (64000 B) during stages A/B, then is
    // overlaid with transformer weights + K/V buffers in stage C.
    __shared__ __align__(16) float s_big[16000];
    __shared__ __align__(16) float s_T[190*11];   // conv2 out == transformer state, padded 10->11
    __shared__ __align__(16) float s_W[1720];     // stage A weights, then stage B weights

    const int tid = threadIdx.x;
    const int b   = blockIdx.x;

    float* H = s_big;   // [16][1000]

    // ---------------- Stage A weights: change (22x16) + CA proj/LN ----------------
    cload(s_W +   0, CWg, 352);   // change_w [22][16]
    cload(s_W + 352, CBg,  16);
    cload(s_W + 368, PWg, 256);   // ca_p_w [16][16]
    cload(s_W + 624, PBg,  16);
    cload(s_W + 640, PGg,  16);
    cload(s_W + 656, PBEg, 16);
    __syncthreads();

    // ---------------- Stage A: h = x@cw+cb ; 4x { h += LN(h@pw+pb) } --------------
    // (channel attention collapses: softmax rows sum to 1, so einsum output == x)
    {
        const float* CW  = s_W;        const float* CB  = s_W + 352;
        const float* PW  = s_W + 368;  const float* PB  = s_W + 624;
        const float* PG  = s_W + 640;  const float* PBE = s_W + 656;
        for (int s = tid; s < 1000; s += 256){
            const float2* xu = (const float2*)(X + (size_t)b*22000 + s*22);
            float xv[22];
#pragma unroll
            for (int j = 0; j < 11; ++j){
                float2 u = xu[j];
                xv[2*j] = u.x; xv[2*j+1] = u.y;
            }
            float v[16];
#pragma unroll
            for (int c = 0; c < 16; ++c){
                float a = CB[c];
#pragma unroll
                for (int j = 0; j < 22; ++j) a += xv[j] * CW[j*16 + c];
                v[c] = a;
            }
            for (int it = 0; it < 4; ++it){
                float u[16]; float m = 0.f;
#pragma unroll
                for (int c = 0; c < 16; ++c){
                    float a = PB[c];
#pragma unroll
                    for (int j = 0; j < 16; ++j) a += v[j] * PW[j*16 + c];
                    u[c] = a; m += a;
                }
                m *= (1.f/16.f);
                float var = 0.f;
#pragma unroll
                for (int c = 0; c < 16; ++c){ float d = u[c] - m; var += d*d; }
                var *= (1.f/16.f);
                float inv = rsqrtf(var + 1e-5f);
#pragma unroll
                for (int c = 0; c < 16; ++c) v[c] += (u[c] - m) * inv * PG[c] + PBE[c];
            }
#pragma unroll
            for (int c = 0; c < 16; ++c) H[c*1000 + s] = v[c];
        }
    }
    __syncthreads();

    // ---------------- Stage B weights: conv1 + folded BN + conv2 ------------------
    cload(s_W +   0, W1g,  102);    // conv1_w [2][51]
    cload(s_W + 108, W2g, 1600);    // conv2_w [10][2][16][5]
    cload(s_W +1708, B2g,   10);    // conv2_b
    if (tid < 2){
        float g  = BNGg[tid], bb = BNBg[tid];
        float mn = BNMg[tid], vr = BNVg[tid];
        float b1 = B1g[tid];
        float sc = g * rsqrtf(vr + 1e-5f);
        s_W[104 + tid] = sc;                     // scale
        s_W[106 + tid] = bb + (b1 - mn) * sc;    // shift (conv1_b folded in)
    }
    __syncthreads();

    // ---------------- Stage B: conv1 -> BN -> LeakyReLU -> conv2 -> t -------------
    if (tid < 190){
        const int w = tid;
        const float* W1 = s_W;
        const float* SC = s_W + 104; const float* SH = s_W + 106;
        const float* W2 = s_W + 108; const float* B2 = s_W + 1708;
        float acc[10];
#pragma unroll
        for (int o = 0; o < 10; ++o) acc[o] = B2[o];
        for (int kh = 0; kh < 16; ++kh){
            float hh[55];
#pragma unroll
            for (int j = 0; j < 55; ++j) hh[j] = H[kh*1000 + 5*w + j];
            float val[2][5];
#pragma unroll
            for (int i = 0; i < 2; ++i){
#pragma unroll
                for (int kw = 0; kw < 5; ++kw){
                    float s = 0.f;
#pragma unroll
                    for (int k = 0; k < 51; ++k) s += hh[kw + k] * W1[i*51 + k];
                    s = s * SC[i] + SH[i];
                    val[i][kw] = s > 0.f ? s : 0.2f * s;
                }
            }
#pragma unroll
            for (int o = 0; o < 10; ++o){
                float s = acc[o];
#pragma unroll
                for (int i = 0; i < 2; ++i)
#pragma unroll
                    for (int kw = 0; kw < 5; ++kw)
                        s += val[i][kw] * W2[((o*2 + i)*16 + kh)*5 + kw];
                acc[o] = s;
            }
        }
#pragma unroll
        for (int o = 0; o < 10; ++o) s_T[w*11 + o] = acc[o];
    }
    __syncthreads();   // stage B done reading H; t written

    // ---------------- Stage C weights over dead h region --------------------------
    float* TW = s_big;              // 3990 f32
    float* KB = s_big + 4000;      // [190][11]
    float* VB = s_big + 4000 + 190*11;
    cload3(TW,    0, LN1Gg,  10);  cload3(TW,   10, LN1Bg,  10);
    cload3(TW,   20, QWg,   100);  cload3(TW,  120, QBg,    10);
    cload3(TW,  130, KWg,   100);  cload3(TW,  230, KBg,    10);
    cload3(TW,  240, VWg,   100);  cload3(TW,  340, VBg,    10);
    cload3(TW,  350, OWg,   100);  cload3(TW,  450, OBg,    10);
    cload3(TW,  460, LN2Gg,  10);  cload3(TW,  470, LN2Bg,  10);
    cload3(TW,  480, F1Wg,  400);  cload3(TW,  880, F1Bg,   40);
    cload3(TW,  920, F2Wg,  400);  cload3(TW, 1320, F2Bg,   10);
    __syncthreads();

    // ---------------- Stage C: 3 transformer encoder layers (n=190, e=10, 5 heads)
    const float SCALE = 0.31622776601683794f;   // 1/sqrt(10)
    const bool act = (tid < 190);
    for (int L = 0; L < 3; ++L){
        const float* W = TW + L*1330;
        float tv[10], q[10];
        if (act){
            float y[10];
#pragma unroll
            for (int c = 0; c < 10; ++c) tv[c] = s_T[tid*11 + c];
            ln10(tv, y, W + 0, W + 10);
#pragma unroll
            for (int c = 0; c < 10; ++c){
                float aq = W[120 + c], ak = W[230 + c], av = W[340 + c];
#pragma unroll
                for (int j = 0; j < 10; ++j){
                    aq += y[j] * W[ 20 + j*10 + c];
                    ak += y[j] * W[130 + j*10 + c];
                    av += y[j] * W[240 + j*10 + c];
                }
                q[c] = aq;
                KB[tid*11 + c] = ak;
                VB[tid*11 + c] = av;
            }
        }
        __syncthreads();
        if (act){
            float outv[10];
#pragma unroll
            for (int h5 = 0; h5 < 5; ++h5){
                float q0 = q[2*h5] * SCALE, q1 = q[2*h5 + 1] * SCALE;
                float m = -1e30f;
                for (int kk = 0; kk < 190; ++kk){
                    float e = q0 * KB[kk*11 + 2*h5] + q1 * KB[kk*11 + 2*h5 + 1];
                    m = fmaxf(m, e);
                }
                float l = 0.f, a0 = 0.f, a1 = 0.f;
                for (int kk = 0; kk < 190; ++kk){
                    float e = q0 * KB[kk*11 + 2*h5] + q1 * KB[kk*11 + 2*h5 + 1];
                    float p = __expf(e - m);
                    l  += p;
                    a0 += p * VB[kk*11 + 2*h5];
                    a1 += p * VB[kk*11 + 2*h5 + 1];
                }
                float rl = 1.f / l;
                outv[2*h5]     = a0 * rl;
                outv[2*h5 + 1] = a1 * rl;
            }
            // output proj + residual
#pragma unroll
            for (int c = 0; c < 10; ++c){
                float a = W[450 + c];
#pragma unroll
                for (int j = 0; j < 10; ++j) a += outv[j] * W[350 + j*10 + c];
                tv[c] += a;
            }
            // FF block
            float y2[10];
            ln10(tv, y2, W + 460, W + 470);
            float g40[40];
#pragma unroll
            for (int j = 0; j < 40; ++j){
                float a = W[880 + j];
#pragma unroll
                for (int c = 0; c < 10; ++c) a += y2[c] * W[480 + c*40 + j];
                g40[j] = 0.5f * a * (1.f + erff(a * 0.70710678118654752f));  // exact GELU
            }
#pragma unroll
            for (int c = 0; c < 10; ++c){
                float a = W[1320 + c];
#pragma unroll
                for (int j = 0; j < 40; ++j) a += g40[j] * W[920 + j*10 + c];
                tv[c] += a;
            }
#pragma unroll
            for (int c = 0; c < 10; ++c) s_T[tid*11 + c] = tv[c];
        }
        __syncthreads();
    }

    // ---------------- Output: t [b,190,10] f32 ------------------------------------
    if (act){
#pragma unroll
        for (int c = 0; c < 10; ++c)
            OUT[(size_t)b*1900 + tid*10 + c] = s_T[tid*11 + c];
    }
}

extern "C" void kernel_launch(void* const* d_in, const int* in_sizes, int n_in,
                              void* d_out, int out_size, void* d_ws, size_t ws_size,
                              hipStream_t stream)
{
    (void)d_ws; (void)ws_size; (void)n_in; (void)out_size;
    const int B = in_sizes[0] / 22000;   // 512
    auto in = [&](int i){ return (const float*)d_in[i]; };
    featurer_kernel<<<B, 256, 0, stream>>>(
        in(0),  in(1),  in(2),
        in(11), in(12), in(13), in(14),
        in(15), in(16), in(17), in(18), in(19), in(20),
        in(21), in(22),
        in(23), in(24), in(25), in(26), in(27), in(28), in(29), in(30),
        in(31), in(32), in(33), in(34), in(35), in(36), in(37), in(38),
        (float*)d_out);
}

// Round 3
// 1015.146 us; speedup vs baseline: 1.0180x; 1.0180x over previous
//
#include <hip/hip_runtime.h>

using ushort_t = unsigned short;

__device__ __forceinline__ float u2f(ushort_t u){
    union{unsigned int i; float f;} x; x.i = ((unsigned int)u) << 16; return x.f;
}
__device__ __forceinline__ ushort_t f2u(float f){   // f32 -> bf16 bits, RNE
    union{float fl; unsigned int i;} x; x.fl = f;
    unsigned int r = x.i + 0x7FFFu + ((x.i >> 16) & 1u);
    return (ushort_t)(r >> 16);
}

__device__ __forceinline__ void cload(float* dst, const float* src, int n){
    for (int i = threadIdx.x; i < n; i += 256) dst[i] = src[i];
}
// scatter a (3, n) array into per-layer blocks of stride 1330 at offset `off`
__device__ __forceinline__ void cload3(float* TW, int off, const float* src, int n){
    for (int i = threadIdx.x; i < 3*n; i += 256){
        int L = i / n, j = i - L*n;
        TW[L*1330 + off + j] = src[i];
    }
}

__device__ __forceinline__ void ln10(const float* in, float* out, const float* g, const float* b){
    float m = 0.f;
#pragma unroll
    for (int c = 0; c < 10; ++c) m += in[c];
    m *= 0.1f;
    float v = 0.f;
#pragma unroll
    for (int c = 0; c < 10; ++c){ float d = in[c] - m; v += d*d; }
    v *= 0.1f;
    float inv = rsqrtf(v + 1e-5f);
#pragma unroll
    for (int c = 0; c < 10; ++c) out[c] = (in[c] - m) * inv * g[c] + b[c];
}

// ---------------- Kernel 1: h = x@cw+cb ; 4x { h += LN(h@pw+pb) } -> ws (bf16) ----
// (channel attention collapses: softmax rows sum to 1 over the summed-out axis,
//  so the einsum output == x; only the projection+LN residual survives)
__global__ __launch_bounds__(256)
void k_embed(const float* __restrict__ X,
             const float* __restrict__ CWg, const float* __restrict__ CBg,
             const float* __restrict__ PWg, const float* __restrict__ PBg,
             const float* __restrict__ PGg, const float* __restrict__ PBEg,
             ushort_t* __restrict__ Hws)
{
    __shared__ __align__(16) float sW[672];
    cload(sW +   0, CWg, 352);
    cload(sW + 352, CBg,  16);
    cload(sW + 368, PWg, 256);
    cload(sW + 624, PBg,  16);
    cload(sW + 640, PGg,  16);
    cload(sW + 656, PBEg, 16);
    __syncthreads();

    const float* CW  = sW;        const float* CB  = sW + 352;
    const float* PW  = sW + 368;  const float* PB  = sW + 624;
    const float* PG  = sW + 640;  const float* PBE = sW + 656;

    const int idx = blockIdx.x * 256 + threadIdx.x;   // 0..511999, grid exact
    const int b = idx / 1000, s = idx - b * 1000;

    const float2* xu = (const float2*)(X + (size_t)idx * 22);
    float xv[22];
#pragma unroll
    for (int j = 0; j < 11; ++j){
        float2 u = xu[j];
        xv[2*j] = u.x; xv[2*j+1] = u.y;
    }
    float v[16];
#pragma unroll
    for (int c = 0; c < 16; ++c){
        float a = CB[c];
#pragma unroll
        for (int j = 0; j < 22; ++j) a += xv[j] * CW[j*16 + c];
        v[c] = a;
    }
    for (int it = 0; it < 4; ++it){
        float u[16]; float m = 0.f;
#pragma unroll
        for (int c = 0; c < 16; ++c){
            float a = PB[c];
#pragma unroll
            for (int j = 0; j < 16; ++j) a += v[j] * PW[j*16 + c];
            u[c] = a; m += a;
        }
        m *= (1.f/16.f);
        float var = 0.f;
#pragma unroll
        for (int c = 0; c < 16; ++c){ float d = u[c] - m; var += d*d; }
        var *= (1.f/16.f);
        float inv = rsqrtf(var + 1e-5f);
#pragma unroll
        for (int c = 0; c < 16; ++c) v[c] += (u[c] - m) * inv * PG[c] + PBE[c];
    }
#pragma unroll
    for (int c = 0; c < 16; ++c)
        Hws[b*16000 + c*1000 + s] = f2u(v[c]);   // lanes -> consecutive s: coalesced
}

// ---------------- Kernel 2: conv1+BN+LReLU+conv2, then 3 transformer layers -------
__global__ __launch_bounds__(256)
void k_main(const ushort_t* __restrict__ Hws,
            const float* __restrict__ W1g, const float* __restrict__ B1g,
            const float* __restrict__ BNGg, const float* __restrict__ BNBg,
            const float* __restrict__ BNMg, const float* __restrict__ BNVg,
            const float* __restrict__ W2g, const float* __restrict__ B2g,
            const float* __restrict__ LN1Gg, const float* __restrict__ LN1Bg,
            const float* __restrict__ QWg, const float* __restrict__ QBg,
            const float* __restrict__ KWg, const float* __restrict__ KBg,
            const float* __restrict__ VWg, const float* __restrict__ VBg,
            const float* __restrict__ OWg, const float* __restrict__ OBg,
            const float* __restrict__ LN2Gg, const float* __restrict__ LN2Bg,
            const float* __restrict__ F1Wg, const float* __restrict__ F1Bg,
            const float* __restrict__ F2Wg, const float* __restrict__ F2Bg,
            float* __restrict__ OUT)
{
    __shared__ __align__(16) float sH[16000];   // h[16][1000] f32; overlaid in stage C
    __shared__ __align__(16) float sW[1720];    // conv weights

    const int tid = threadIdx.x;
    const int b   = blockIdx.x;

    // stage h (bf16 ws -> f32 LDS) + conv weights
    for (int i = tid; i < 16000; i += 256) sH[i] = u2f(Hws[b*16000 + i]);
    cload(sW +   0, W1g,  102);    // conv1_w [2][51]
    cload(sW + 108, W2g, 1600);    // conv2_w [10][2][16][5]
    cload(sW +1708, B2g,   10);    // conv2_b
    if (tid < 2){
        float g  = BNGg[tid], bb = BNBg[tid];
        float mn = BNMg[tid], vr = BNVg[tid];
        float b1 = B1g[tid];
        float sc = g * rsqrtf(vr + 1e-5f);
        sW[104 + tid] = sc;                     // scale
        sW[106 + tid] = bb + (b1 - mn) * sc;    // shift (conv1_b folded in)
    }
    __syncthreads();

    // ---- Stage B: conv1 -> BN -> LeakyReLU -> conv2 (acc stays in registers) ----
    float acc[10];
    if (tid < 190){
        const int w = tid;
        const float* W1 = sW;
        const float* SC = sW + 104; const float* SH = sW + 106;
        const float* W2 = sW + 108; const float* B2 = sW + 1708;
#pragma unroll
        for (int o = 0; o < 10; ++o) acc[o] = B2[o];
        for (int kh = 0; kh < 16; ++kh){
            float hh[55];
#pragma unroll
            for (int j = 0; j < 55; ++j) hh[j] = sH[kh*1000 + 5*w + j];
            float val[2][5];
#pragma unroll
            for (int i = 0; i < 2; ++i){
#pragma unroll
                for (int kw = 0; kw < 5; ++kw){
                    float s = 0.f;
#pragma unroll
                    for (int k = 0; k < 51; ++k) s += hh[kw + k] * W1[i*51 + k];
                    s = s * SC[i] + SH[i];
                    val[i][kw] = s > 0.f ? s : 0.2f * s;
                }
            }
#pragma unroll
            for (int o = 0; o < 10; ++o){
                float s = acc[o];
#pragma unroll
                for (int i = 0; i < 2; ++i)
#pragma unroll
                    for (int kw = 0; kw < 5; ++kw)
                        s += val[i][kw] * W2[((o*2 + i)*16 + kh)*5 + kw];
                acc[o] = s;
            }
        }
    }
    __syncthreads();   // all reads of sH done; safe to overlay

    // ---- Stage C memory plan over dead h region ----
    float* TW = sH;              // 3990 f32 transformer weights
    float* T  = sH + 4000;       // [190][11] state
    float* KB = sH + 6100;       // [190][11]
    float* VB = sH + 8200;       // [190][11]
    if (tid < 190){
#pragma unroll
        for (int o = 0; o < 10; ++o) T[tid*11 + o] = acc[o];
    }
    cload3(TW,    0, LN1Gg,  10);  cload3(TW,   10, LN1Bg,  10);
    cload3(TW,   20, QWg,   100);  cload3(TW,  120, QBg,    10);
    cload3(TW,  130, KWg,   100);  cload3(TW,  230, KBg,    10);
    cload3(TW,  240, VWg,   100);  cload3(TW,  340, VBg,    10);
    cload3(TW,  350, OWg,   100);  cload3(TW,  450, OBg,    10);
    cload3(TW,  460, LN2Gg,  10);  cload3(TW,  470, LN2Bg,  10);
    cload3(TW,  480, F1Wg,  400);  cload3(TW,  880, F1Bg,   40);
    cload3(TW,  920, F2Wg,  400);  cload3(TW, 1320, F2Bg,   10);
    __syncthreads();

    // ---- Stage C: 3 transformer encoder layers (n=190, e=10, 5 heads, d=2) ----
    const float SCALE = 0.31622776601683794f;   // 1/sqrt(10)
    const bool act = (tid < 190);
    for (int L = 0; L < 3; ++L){
        const float* W = TW + L*1330;
        float tv[10], q[10];
        if (act){
            float y[10];
#pragma unroll
            for (int c = 0; c < 10; ++c) tv[c] = T[tid*11 + c];
            ln10(tv, y, W + 0, W + 10);
#pragma unroll
            for (int c = 0; c < 10; ++c){
                float aq = W[120 + c], ak = W[230 + c], av = W[340 + c];
#pragma unroll
                for (int j = 0; j < 10; ++j){
                    aq += y[j] * W[ 20 + j*10 + c];
                    ak += y[j] * W[130 + j*10 + c];
                    av += y[j] * W[240 + j*10 + c];
                }
                q[c] = aq;
                KB[tid*11 + c] = ak;
                VB[tid*11 + c] = av;
            }
        }
        __syncthreads();
        if (act){
            float outv[10];
#pragma unroll
            for (int h5 = 0; h5 < 5; ++h5){
                float q0 = q[2*h5] * SCALE, q1 = q[2*h5 + 1] * SCALE;
                float m = -1e30f;
                for (int kk = 0; kk < 190; ++kk){
                    float e = q0 * KB[kk*11 + 2*h5] + q1 * KB[kk*11 + 2*h5 + 1];
                    m = fmaxf(m, e);
                }
                float l = 0.f, a0 = 0.f, a1 = 0.f;
                for (int kk = 0; kk < 190; ++kk){
                    float e = q0 * KB[kk*11 + 2*h5] + q1 * KB[kk*11 + 2*h5 + 1];
                    float p = __expf(e - m);
                    l  += p;
                    a0 += p * VB[kk*11 + 2*h5];
                    a1 += p * VB[kk*11 + 2*h5 + 1];
                }
                float rl = 1.f / l;
                outv[2*h5]     = a0 * rl;
                outv[2*h5 + 1] = a1 * rl;
            }
#pragma unroll
            for (int c = 0; c < 10; ++c){
                float a = W[450 + c];
#pragma unroll
                for (int j = 0; j < 10; ++j) a += outv[j] * W[350 + j*10 + c];
                tv[c] += a;
            }
            float y2[10];
            ln10(tv, y2, W + 460, W + 470);
            float g40[40];
#pragma unroll
            for (int j = 0; j < 40; ++j){
                float a = W[880 + j];
#pragma unroll
                for (int c = 0; c < 10; ++c) a += y2[c] * W[480 + c*40 + j];
                g40[j] = 0.5f * a * (1.f + erff(a * 0.70710678118654752f));  // exact GELU
            }
#pragma unroll
            for (int c = 0; c < 10; ++c){
                float a = W[1320 + c];
#pragma unroll
                for (int j = 0; j < 40; ++j) a += g40[j] * W[920 + j*10 + c];
                tv[c] += a;
            }
#pragma unroll
            for (int c = 0; c < 10; ++c) T[tid*11 + c] = tv[c];
        }
        __syncthreads();
    }

    if (act){
#pragma unroll
        for (int c = 0; c < 10; ++c)
            OUT[(size_t)b*1900 + tid*10 + c] = T[tid*11 + c];
    }
}

extern "C" void kernel_launch(void* const* d_in, const int* in_sizes, int n_in,
                              void* d_out, int out_size, void* d_ws, size_t ws_size,
                              hipStream_t stream)
{
    (void)ws_size; (void)n_in; (void)out_size;
    const int B = in_sizes[0] / 22000;   // 512
    auto in = [&](int i){ return (const float*)d_in[i]; };
    ushort_t* Hws = (ushort_t*)d_ws;     // B*16*1000 bf16 = 16.4 MB

    k_embed<<<(B * 1000) / 256 + ((B*1000)%256?1:0), 256, 0, stream>>>(
        in(0), in(1), in(2), in(11), in(12), in(13), in(14), Hws);

    k_main<<<B, 256, 0, stream>>>(
        Hws,
        in(15), in(16), in(17), in(18), in(19), in(20),
        in(21), in(22),
        in(23), in(24), in(25), in(26), in(27), in(28), in(29), in(30),
        in(31), in(32), in(33), in(34), in(35), in(36), in(37), in(38),
        (float*)d_out);
}

// Round 4
// 568.693 us; speedup vs baseline: 1.8172x; 1.7851x over previous
//
#include <hip/hip_runtime.h>

using ushort_t = unsigned short;

__device__ __forceinline__ float u2f(ushort_t u){
    union{unsigned int i; float f;} x; x.i = ((unsigned int)u) << 16; return x.f;
}
__device__ __forceinline__ ushort_t f2u(float f){   // f32 -> bf16 bits, RNE
    union{float fl; unsigned int i;} x; x.fl = f;
    unsigned int r = x.i + 0x7FFFu + ((x.i >> 16) & 1u);
    return (ushort_t)(r >> 16);
}

__device__ __forceinline__ void cload(float* dst, const float* src, int n){
    for (int i = threadIdx.x; i < n; i += 256) dst[i] = src[i];
}
// scatter a (3, n) array into per-layer blocks of stride 1330 at offset `off`
__device__ __forceinline__ void cload3(float* TW, int off, const float* src, int n){
    for (int i = threadIdx.x; i < 3*n; i += 256){
        int L = i / n, j = i - L*n;
        TW[L*1330 + off + j] = src[i];
    }
}

__device__ __forceinline__ void ln10(const float* in, float* out, const float* g, const float* b){
    float m = 0.f;
#pragma unroll
    for (int c = 0; c < 10; ++c) m += in[c];
    m *= 0.1f;
    float v = 0.f;
#pragma unroll
    for (int c = 0; c < 10; ++c){ float d = in[c] - m; v += d*d; }
    v *= 0.1f;
    float inv = rsqrtf(v + 1e-5f);
#pragma unroll
    for (int c = 0; c < 10; ++c) out[c] = (in[c] - m) * inv * g[c] + b[c];
}

// ---------------- Kernel 1: h = x@cw+cb ; 4x { h += LN(h@pw+pb) } -> ws (bf16) ----
// (channel attention collapses: softmax rows sum to 1 over the summed-out axis,
//  so the einsum output == x; only the projection+LN residual survives)
__global__ __launch_bounds__(256)
void k_embed(const float* __restrict__ X,
             const float* __restrict__ CWg, const float* __restrict__ CBg,
             const float* __restrict__ PWg, const float* __restrict__ PBg,
             const float* __restrict__ PGg, const float* __restrict__ PBEg,
             ushort_t* __restrict__ Hws)
{
    __shared__ __align__(16) float sW[672];
    cload(sW +   0, CWg, 352);
    cload(sW + 352, CBg,  16);
    cload(sW + 368, PWg, 256);
    cload(sW + 624, PBg,  16);
    cload(sW + 640, PGg,  16);
    cload(sW + 656, PBEg, 16);
    __syncthreads();

    const float* CW  = sW;        const float* CB  = sW + 352;
    const float* PW  = sW + 368;  const float* PB  = sW + 624;
    const float* PG  = sW + 640;  const float* PBE = sW + 656;

    const int idx = blockIdx.x * 256 + threadIdx.x;   // 0..511999, grid exact
    const int b = idx / 1000, s = idx - b * 1000;

    const float2* xu = (const float2*)(X + (size_t)idx * 22);
    float xv[22];
#pragma unroll
    for (int j = 0; j < 11; ++j){
        float2 u = xu[j];
        xv[2*j] = u.x; xv[2*j+1] = u.y;
    }
    float v[16];
#pragma unroll
    for (int c = 0; c < 16; ++c){
        float a = CB[c];
#pragma unroll
        for (int j = 0; j < 22; ++j) a += xv[j] * CW[j*16 + c];
        v[c] = a;
    }
    for (int it = 0; it < 4; ++it){
        float u[16]; float m = 0.f;
#pragma unroll
        for (int c = 0; c < 16; ++c){
            float a = PB[c];
#pragma unroll
            for (int j = 0; j < 16; ++j) a += v[j] * PW[j*16 + c];
            u[c] = a; m += a;
        }
        m *= (1.f/16.f);
        float var = 0.f;
#pragma unroll
        for (int c = 0; c < 16; ++c){ float d = u[c] - m; var += d*d; }
        var *= (1.f/16.f);
        float inv = rsqrtf(var + 1e-5f);
#pragma unroll
        for (int c = 0; c < 16; ++c) v[c] += (u[c] - m) * inv * PG[c] + PBE[c];
    }
#pragma unroll
    for (int c = 0; c < 16; ++c)
        Hws[b*16000 + c*1000 + s] = f2u(v[c]);   // lanes -> consecutive s: coalesced
}

// ---------------- Kernel 2: conv1 -> BN -> LeakyReLU -> conv2 -> t (ws, f32) ------
__global__ __launch_bounds__(256)
void k_conv(const ushort_t* __restrict__ Hws,
            const float* __restrict__ W1g, const float* __restrict__ B1g,
            const float* __restrict__ BNGg, const float* __restrict__ BNBg,
            const float* __restrict__ BNMg, const float* __restrict__ BNVg,
            const float* __restrict__ W2g, const float* __restrict__ B2g,
            float* __restrict__ Tws)
{
    __shared__ __align__(16) float sH[16000];   // h[16][1000] f32
    __shared__ __align__(16) float sW[1720];

    const int tid = threadIdx.x;
    const int b   = blockIdx.x;

    for (int i = tid; i < 16000; i += 256) sH[i] = u2f(Hws[b*16000 + i]);
    cload(sW +   0, W1g,  102);    // conv1_w [2][51]
    cload(sW + 108, W2g, 1600);    // conv2_w [10][2][16][5]
    cload(sW +1708, B2g,   10);    // conv2_b
    if (tid < 2){
        float g  = BNGg[tid], bb = BNBg[tid];
        float mn = BNMg[tid], vr = BNVg[tid];
        float b1 = B1g[tid];
        float sc = g * rsqrtf(vr + 1e-5f);
        sW[104 + tid] = sc;                     // scale
        sW[106 + tid] = bb + (b1 - mn) * sc;    // shift (conv1_b folded in)
    }
    __syncthreads();

    if (tid < 190){
        const int w = tid;
        const float* W1 = sW;
        const float* SC = sW + 104; const float* SH = sW + 106;
        const float* W2 = sW + 108; const float* B2 = sW + 1708;
        float acc[10];
#pragma unroll
        for (int o = 0; o < 10; ++o) acc[o] = B2[o];
        for (int kh = 0; kh < 16; ++kh){
            float hh[55];
#pragma unroll
            for (int j = 0; j < 55; ++j) hh[j] = sH[kh*1000 + 5*w + j];
            float val[2][5];
#pragma unroll
            for (int i = 0; i < 2; ++i){
#pragma unroll
                for (int kw = 0; kw < 5; ++kw){
                    float s = 0.f;
#pragma unroll
                    for (int k = 0; k < 51; ++k) s += hh[kw + k] * W1[i*51 + k];
                    s = s * SC[i] + SH[i];
                    val[i][kw] = s > 0.f ? s : 0.2f * s;
                }
            }
#pragma unroll
            for (int o = 0; o < 10; ++o){
                float s = acc[o];
#pragma unroll
                for (int i = 0; i < 2; ++i)
#pragma unroll
                    for (int kw = 0; kw < 5; ++kw)
                        s += val[i][kw] * W2[((o*2 + i)*16 + kh)*5 + kw];
                acc[o] = s;
            }
        }
#pragma unroll
        for (int o = 0; o < 10; ++o) Tws[(size_t)b*1900 + w*10 + o] = acc[o];
    }
}

// ---------------- Kernel 3: 3 transformer encoder layers (n=190, e=10, 5 heads) ---
__global__ __launch_bounds__(256)
void k_tf(const float* __restrict__ Tws,
          const float* __restrict__ LN1Gg, const float* __restrict__ LN1Bg,
          const float* __restrict__ QWg, const float* __restrict__ QBg,
          const float* __restrict__ KWg, const float* __restrict__ KBg,
          const float* __restrict__ VWg, const float* __restrict__ VBg,
          const float* __restrict__ OWg, const float* __restrict__ OBg,
          const float* __restrict__ LN2Gg, const float* __restrict__ LN2Bg,
          const float* __restrict__ F1Wg, const float* __restrict__ F1Bg,
          const float* __restrict__ F2Wg, const float* __restrict__ F2Bg,
          float* __restrict__ OUT)
{
    __shared__ __align__(16) float TW[4000];   // 3 layers x 1330
    __shared__ __align__(16) float T [2090];   // [190][11]
    __shared__ __align__(16) float QB[2090];
    __shared__ __align__(16) float KB[2090];
    __shared__ __align__(16) float VB[2090];
    __shared__ __align__(16) float AT[2090];

    const int tid = threadIdx.x;
    const int b   = blockIdx.x;

    cload3(TW,    0, LN1Gg,  10);  cload3(TW,   10, LN1Bg,  10);
    cload3(TW,   20, QWg,   100);  cload3(TW,  120, QBg,    10);
    cload3(TW,  130, KWg,   100);  cload3(TW,  230, KBg,    10);
    cload3(TW,  240, VWg,   100);  cload3(TW,  340, VBg,    10);
    cload3(TW,  350, OWg,   100);  cload3(TW,  450, OBg,    10);
    cload3(TW,  460, LN2Gg,  10);  cload3(TW,  470, LN2Bg,  10);
    cload3(TW,  480, F1Wg,  400);  cload3(TW,  880, F1Bg,   40);
    cload3(TW,  920, F2Wg,  400);  cload3(TW, 1320, F2Bg,   10);
    for (int i = tid; i < 1900; i += 256){
        int r = i / 10, c = i - r*10;
        T[r*11 + c] = Tws[(size_t)b*1900 + i];
    }
    __syncthreads();

    const float SCALE = 0.31622776601683794f;   // 1/sqrt(10)
    const bool act = (tid < 190);
    for (int L = 0; L < 3; ++L){
        const float* W = TW + L*1330;
        // ---- phase 1: LN1 + Q/K/V projections (190 threads) ----
        if (act){
            float tv[10], y[10];
#pragma unroll
            for (int c = 0; c < 10; ++c) tv[c] = T[tid*11 + c];
            ln10(tv, y, W + 0, W + 10);
#pragma unroll
            for (int c = 0; c < 10; ++c){
                float aq = W[120 + c], ak = W[230 + c], av = W[340 + c];
#pragma unroll
                for (int j = 0; j < 10; ++j){
                    aq += y[j] * W[ 20 + j*10 + c];
                    ak += y[j] * W[130 + j*10 + c];
                    av += y[j] * W[240 + j*10 + c];
                }
                QB[tid*11 + c] = aq;
                KB[tid*11 + c] = ak;
                VB[tid*11 + c] = av;
            }
        }
        __syncthreads();
        // ---- phase 2: attention over 950 (query, head) pairs, all 256 threads ----
        // softmax without max-subtraction: logits are O(10), exp is safe in f32,
        // and jax's max-shift is mathematically identity on the result.
        for (int p = tid; p < 950; p += 256){
            const int qi = p / 5, h5 = p - qi*5;
            const float q0 = QB[qi*11 + 2*h5]     * SCALE;
            const float q1 = QB[qi*11 + 2*h5 + 1] * SCALE;
            float l = 0.f, a0 = 0.f, a1 = 0.f;
            for (int kk = 0; kk < 190; ++kk){
                float k0 = KB[kk*11 + 2*h5], k1 = KB[kk*11 + 2*h5 + 1];
                float pr = __expf(q0*k0 + q1*k1);
                l  += pr;
                a0 += pr * VB[kk*11 + 2*h5];
                a1 += pr * VB[kk*11 + 2*h5 + 1];
            }
            float rl = 1.f / l;
            AT[qi*11 + 2*h5]     = a0 * rl;
            AT[qi*11 + 2*h5 + 1] = a1 * rl;
        }
        __syncthreads();
        // ---- phase 3: out-proj + residual + LN2 + FF(GELU) + residual ----
        if (act){
            float tv[10];
#pragma unroll
            for (int c = 0; c < 10; ++c) tv[c] = T[tid*11 + c];
#pragma unroll
            for (int c = 0; c < 10; ++c){
                float a = W[450 + c];
#pragma unroll
                for (int j = 0; j < 10; ++j) a += AT[tid*11 + j] * W[350 + j*10 + c];
                tv[c] += a;
            }
            float y2[10];
            ln10(tv, y2, W + 460, W + 470);
            float g40[40];
#pragma unroll
            for (int j = 0; j < 40; ++j){
                float a = W[880 + j];
#pragma unroll
                for (int c = 0; c < 10; ++c) a += y2[c] * W[480 + c*40 + j];
                g40[j] = 0.5f * a * (1.f + erff(a * 0.70710678118654752f));  // exact GELU
            }
#pragma unroll
            for (int c = 0; c < 10; ++c){
                float a = W[1320 + c];
#pragma unroll
                for (int j = 0; j < 40; ++j) a += g40[j] * W[920 + j*10 + c];
                tv[c] += a;
            }
#pragma unroll
            for (int c = 0; c < 10; ++c) T[tid*11 + c] = tv[c];
        }
        __syncthreads();
    }

    if (act){
#pragma unroll
        for (int c = 0; c < 10; ++c)
            OUT[(size_t)b*1900 + tid*10 + c] = T[tid*11 + c];
    }
}

extern "C" void kernel_launch(void* const* d_in, const int* in_sizes, int n_in,
                              void* d_out, int out_size, void* d_ws, size_t ws_size,
                              hipStream_t stream)
{
    (void)ws_size; (void)n_in; (void)out_size;
    const int B = in_sizes[0] / 22000;   // 512
    auto in = [&](int i){ return (const float*)d_in[i]; };
    ushort_t* Hws = (ushort_t*)d_ws;                              // B*16000 bf16 = 16.38 MB
    float*    Tws = (float*)((char*)d_ws + (size_t)B*16000*2);    // B*1900 f32  =  3.89 MB

    k_embed<<<(B*1000 + 255)/256, 256, 0, stream>>>(
        in(0), in(1), in(2), in(11), in(12), in(13), in(14), Hws);

    k_conv<<<B, 256, 0, stream>>>(
        Hws, in(15), in(16), in(17), in(18), in(19), in(20), in(21), in(22), Tws);

    k_tf<<<B, 256, 0, stream>>>(
        Tws,
        in(23), in(24), in(25), in(26), in(27), in(28), in(29), in(30),
        in(31), in(32), in(33), in(34), in(35), in(36), in(37), in(38),
        (float*)d_out);
}

// Round 5
// 487.158 us; speedup vs baseline: 2.1214x; 1.1674x over previous
//
#include <hip/hip_runtime.h>

using ushort_t = unsigned short;

__device__ __forceinline__ float u2f(ushort_t u){
    union{unsigned int i; float f;} x; x.i = ((unsigned int)u) << 16; return x.f;
}
__device__ __forceinline__ ushort_t f2u(float f){   // f32 -> bf16 bits, RNE
    union{float fl; unsigned int i;} x; x.fl = f;
    unsigned int r = x.i + 0x7FFFu + ((x.i >> 16) & 1u);
    return (ushort_t)(r >> 16);
}

// LayerNorm over 10 channels; g/b are GLOBAL pointers (uniform -> s_load)
__device__ __forceinline__ void ln10(const float* in, float* out,
                                     const float* __restrict__ g,
                                     const float* __restrict__ b){
    float m = 0.f;
#pragma unroll
    for (int c = 0; c < 10; ++c) m += in[c];
    m *= 0.1f;
    float v = 0.f;
#pragma unroll
    for (int c = 0; c < 10; ++c){ float d = in[c] - m; v += d*d; }
    v *= 0.1f;
    float inv = rsqrtf(v + 1e-5f);
#pragma unroll
    for (int c = 0; c < 10; ++c) out[c] = (in[c] - m) * inv * g[c] + b[c];
}

// ---------------- Kernel 1: h = x@cw+cb ; 4x { h += LN(h@pw+pb) } -> ws (bf16) ----
// (channel attention collapses: softmax rows sum to 1 over the summed-out axis,
//  so the einsum output == x; only the projection+LN residual survives)
// Weights read straight from global: wave-uniform indices -> scalar loads (K$),
// zero LDS traffic.
__global__ __launch_bounds__(256)
void k_embed(const float* __restrict__ X,
             const float* __restrict__ CW, const float* __restrict__ CB,
             const float* __restrict__ PW, const float* __restrict__ PB,
             const float* __restrict__ PG, const float* __restrict__ PBE,
             ushort_t* __restrict__ Hws)
{
    const int idx = blockIdx.x * 256 + threadIdx.x;   // 0..511999, grid exact
    const int b = idx / 1000, s = idx - b * 1000;

    const float2* xu = (const float2*)(X + (size_t)idx * 22);
    float xv[22];
#pragma unroll
    for (int j = 0; j < 11; ++j){
        float2 u = xu[j];
        xv[2*j] = u.x; xv[2*j+1] = u.y;
    }
    float v[16];
#pragma unroll
    for (int c = 0; c < 16; ++c){
        float a = CB[c];
#pragma unroll
        for (int j = 0; j < 22; ++j) a += xv[j] * CW[j*16 + c];
        v[c] = a;
    }
#pragma unroll
    for (int it = 0; it < 4; ++it){
        float u[16]; float m = 0.f;
#pragma unroll
        for (int c = 0; c < 16; ++c){
            float a = PB[c];
#pragma unroll
            for (int j = 0; j < 16; ++j) a += v[j] * PW[j*16 + c];
            u[c] = a; m += a;
        }
        m *= (1.f/16.f);
        float var = 0.f;
#pragma unroll
        for (int c = 0; c < 16; ++c){ float d = u[c] - m; var += d*d; }
        var *= (1.f/16.f);
        float inv = rsqrtf(var + 1e-5f);
#pragma unroll
        for (int c = 0; c < 16; ++c) v[c] += (u[c] - m) * inv * PG[c] + PBE[c];
    }
#pragma unroll
    for (int c = 0; c < 16; ++c)
        Hws[b*16000 + c*1000 + s] = f2u(v[c]);   // lanes -> consecutive s: coalesced
}

// ---------------- Kernel 2: conv1 -> BN -> LeakyReLU -> conv2 -> t (ws, f32) ------
// LDS holds only h; conv weights via scalar loads from global.
__global__ __launch_bounds__(256)
void k_conv(const ushort_t* __restrict__ Hws,
            const float* __restrict__ W1, const float* __restrict__ B1,
            const float* __restrict__ BNG, const float* __restrict__ BNB,
            const float* __restrict__ BNM, const float* __restrict__ BNV,
            const float* __restrict__ W2, const float* __restrict__ B2,
            float* __restrict__ Tws)
{
    __shared__ __align__(16) float sH[16000];   // h[16][1000] f32

    const int tid = threadIdx.x;
    const int b   = blockIdx.x;

    for (int i = tid; i < 16000; i += 256) sH[i] = u2f(Hws[b*16000 + i]);

    // BN fold (uniform scalars)
    float sc[2], sh[2];
#pragma unroll
    for (int i = 0; i < 2; ++i){
        float s0 = BNG[i] * rsqrtf(BNV[i] + 1e-5f);
        sc[i] = s0;
        sh[i] = BNB[i] + (B1[i] - BNM[i]) * s0;
    }
    __syncthreads();

    if (tid < 190){
        const int w = tid;
        float acc[10];
#pragma unroll
        for (int o = 0; o < 10; ++o) acc[o] = B2[o];
        for (int kh = 0; kh < 16; ++kh){
            float hh[55];
#pragma unroll
            for (int j = 0; j < 55; ++j) hh[j] = sH[kh*1000 + 5*w + j];
            float val[2][5];
#pragma unroll
            for (int i = 0; i < 2; ++i){
#pragma unroll
                for (int kw = 0; kw < 5; ++kw){
                    float s = 0.f;
#pragma unroll
                    for (int k = 0; k < 51; ++k) s += hh[kw + k] * W1[i*51 + k];
                    s = s * sc[i] + sh[i];
                    val[i][kw] = s > 0.f ? s : 0.2f * s;
                }
            }
#pragma unroll
            for (int o = 0; o < 10; ++o){
                float s = acc[o];
#pragma unroll
                for (int i = 0; i < 2; ++i)
#pragma unroll
                    for (int kw = 0; kw < 5; ++kw)
                        s += val[i][kw] * W2[((o*2 + i)*16 + kh)*5 + kw];
                acc[o] = s;
            }
        }
#pragma unroll
        for (int o = 0; o < 10; ++o) Tws[(size_t)b*1900 + w*10 + o] = acc[o];
    }
}

// ---------------- Kernel 3: 3 transformer encoder layers (n=190, e=10, 5 heads) ---
// LDS: T (stride 11) + Q/K/V/AT (stride 12 -> aligned float2 pairs per head).
// All weights via scalar loads. Attention is head-major: thread = (head, 4 queries)
// sharing one K/V stream -> 2 ds_read_b64 per k-step for 4 queries.
__global__ __launch_bounds__(256)
void k_tf(const float* __restrict__ Tws,
          const float* __restrict__ LN1G, const float* __restrict__ LN1B,
          const float* __restrict__ QW, const float* __restrict__ QBv,
          const float* __restrict__ KW, const float* __restrict__ KBv,
          const float* __restrict__ VW, const float* __restrict__ VBv,
          const float* __restrict__ OW, const float* __restrict__ OBv,
          const float* __restrict__ LN2G, const float* __restrict__ LN2B,
          const float* __restrict__ F1W, const float* __restrict__ F1B,
          const float* __restrict__ F2W, const float* __restrict__ F2B,
          float* __restrict__ OUT)
{
    __shared__ __align__(16) float T [190*11];
    __shared__ __align__(16) float QB[190*12];
    __shared__ __align__(16) float KB[190*12];
    __shared__ __align__(16) float VB[190*12];
    __shared__ __align__(16) float AT[190*12];

    const int tid = threadIdx.x;
    const int b   = blockIdx.x;

    for (int i = tid; i < 1900; i += 256){
        int r = i / 10, c = i - r*10;
        T[r*11 + c] = Tws[(size_t)b*1900 + i];
    }
    __syncthreads();

    const float SCALE = 0.31622776601683794f;   // 1/sqrt(10)
    const bool act = (tid < 190);
    for (int L = 0; L < 3; ++L){
        const float* ln1g = LN1G + L*10; const float* ln1b = LN1B + L*10;
        const float* qw = QW + L*100;    const float* qb = QBv + L*10;
        const float* kw = KW + L*100;    const float* kb = KBv + L*10;
        const float* vw = VW + L*100;    const float* vb = VBv + L*10;
        const float* ow = OW + L*100;    const float* ob = OBv + L*10;
        const float* ln2g = LN2G + L*10; const float* ln2b = LN2B + L*10;
        const float* f1w = F1W + L*400;  const float* f1b = F1B + L*40;
        const float* f2w = F2W + L*400;  const float* f2b = F2B + L*10;

        // ---- phase 1: LN1 + Q/K/V projections (190 threads) ----
        if (act){
            float tv[10], y[10];
#pragma unroll
            for (int c = 0; c < 10; ++c) tv[c] = T[tid*11 + c];
            ln10(tv, y, ln1g, ln1b);
#pragma unroll
            for (int c = 0; c < 10; ++c){
                float aq = qb[c], ak = kb[c], av = vb[c];
#pragma unroll
                for (int j = 0; j < 10; ++j){
                    aq += y[j] * qw[j*10 + c];
                    ak += y[j] * kw[j*10 + c];
                    av += y[j] * vw[j*10 + c];
                }
                QB[tid*12 + c] = aq;
                KB[tid*12 + c] = ak;
                VB[tid*12 + c] = av;
            }
        }
        __syncthreads();

        // ---- phase 2: attention, head-major (240 threads: head = tid/48) ----
        // no-max softmax: logits are O(1); jax's max-shift is mathematically identity.
        if (tid < 240){
            const int h5 = tid / 48;
            const int qg = tid - h5*48;      // 0..47
            const int q0 = qg * 4;           // 4 queries per thread
            float qx[4], qy[4];
#pragma unroll
            for (int i = 0; i < 4; ++i){
                int qi = q0 + i;
                if (qi < 190){
                    qx[i] = QB[qi*12 + 2*h5]     * SCALE;
                    qy[i] = QB[qi*12 + 2*h5 + 1] * SCALE;
                } else { qx[i] = 0.f; qy[i] = 0.f; }
            }
            float l[4] = {0,0,0,0}, a0[4] = {0,0,0,0}, a1[4] = {0,0,0,0};
            for (int kk = 0; kk < 190; ++kk){
                float2 kv = *(const float2*)&KB[kk*12 + 2*h5];
                float2 vv = *(const float2*)&VB[kk*12 + 2*h5];
#pragma unroll
                for (int i = 0; i < 4; ++i){
                    float p = __expf(qx[i]*kv.x + qy[i]*kv.y);
                    l[i] += p; a0[i] += p*vv.x; a1[i] += p*vv.y;
                }
            }
#pragma unroll
            for (int i = 0; i < 4; ++i){
                int qi = q0 + i;
                if (qi < 190){
                    float rl = 1.f / l[i];
                    AT[qi*12 + 2*h5]     = a0[i] * rl;
                    AT[qi*12 + 2*h5 + 1] = a1[i] * rl;
                }
            }
        }
        __syncthreads();

        // ---- phase 3: out-proj + residual + LN2 + FF(GELU) + residual ----
        if (act){
            float tv[10], at[10];
#pragma unroll
            for (int c = 0; c < 10; ++c){ tv[c] = T[tid*11 + c]; at[c] = AT[tid*12 + c]; }
#pragma unroll
            for (int c = 0; c < 10; ++c){
                float a = ob[c];
#pragma unroll
                for (int j = 0; j < 10; ++j) a += at[j] * ow[j*10 + c];
                tv[c] += a;
            }
            float y2[10];
            ln10(tv, y2, ln2g, ln2b);
            float g40[40];
#pragma unroll
            for (int j = 0; j < 40; ++j){
                float a = f1b[j];
#pragma unroll
                for (int c = 0; c < 10; ++c) a += y2[c] * f1w[c*40 + j];
                g40[j] = 0.5f * a * (1.f + erff(a * 0.70710678118654752f));  // exact GELU
            }
#pragma unroll
            for (int c = 0; c < 10; ++c){
                float a = f2b[c];
#pragma unroll
                for (int j = 0; j < 40; ++j) a += g40[j] * f2w[j*10 + c];
                tv[c] += a;
            }
#pragma unroll
            for (int c = 0; c < 10; ++c) T[tid*11 + c] = tv[c];
        }
        __syncthreads();
    }

    if (act){
#pragma unroll
        for (int c = 0; c < 10; ++c)
            OUT[(size_t)b*1900 + tid*10 + c] = T[tid*11 + c];
    }
}

extern "C" void kernel_launch(void* const* d_in, const int* in_sizes, int n_in,
                              void* d_out, int out_size, void* d_ws, size_t ws_size,
                              hipStream_t stream)
{
    (void)ws_size; (void)n_in; (void)out_size;
    const int B = in_sizes[0] / 22000;   // 512
    auto in = [&](int i){ return (const float*)d_in[i]; };
    ushort_t* Hws = (ushort_t*)d_ws;                              // B*16000 bf16 = 16.38 MB
    float*    Tws = (float*)((char*)d_ws + (size_t)B*16000*2);    // B*1900 f32  =  3.89 MB

    k_embed<<<(B*1000 + 255)/256, 256, 0, stream>>>(
        in(0), in(1), in(2), in(11), in(12), in(13), in(14), Hws);

    k_conv<<<B, 256, 0, stream>>>(
        Hws, in(15), in(16), in(17), in(18), in(19), in(20), in(21), in(22), Tws);

    k_tf<<<B, 256, 0, stream>>>(
        Tws,
        in(23), in(24), in(25), in(26), in(27), in(28), in(29), in(30),
        in(31), in(32), in(33), in(34), in(35), in(36), in(37), in(38),
        (float*)d_out);
}

// Round 6
// 485.472 us; speedup vs baseline: 2.1288x; 1.0035x over previous
//
#include <hip/hip_runtime.h>

using ushort_t = unsigned short;

__device__ __forceinline__ float u2f(ushort_t u){
    union{unsigned int i; float f;} x; x.i = ((unsigned int)u) << 16; return x.f;
}
__device__ __forceinline__ ushort_t f2u(float f){   // f32 -> bf16 bits, RNE
    union{float fl; unsigned int i;} x; x.fl = f;
    unsigned int r = x.i + 0x7FFFu + ((x.i >> 16) & 1u);
    return (ushort_t)(r >> 16);
}

// LayerNorm over 10 channels; g/b are GLOBAL pointers (uniform -> s_load)
__device__ __forceinline__ void ln10(const float* in, float* out,
                                     const float* __restrict__ g,
                                     const float* __restrict__ b){
    float m = 0.f;
#pragma unroll
    for (int c = 0; c < 10; ++c) m += in[c];
    m *= 0.1f;
    float v = 0.f;
#pragma unroll
    for (int c = 0; c < 10; ++c){ float d = in[c] - m; v += d*d; }
    v *= 0.1f;
    float inv = rsqrtf(v + 1e-5f);
#pragma unroll
    for (int c = 0; c < 10; ++c) out[c] = (in[c] - m) * inv * g[c] + b[c];
}

// ---------------- Kernel 1: h = x@cw+cb ; 4x { h += LN(h@pw+pb) } -> ws (bf16) ----
// (channel attention collapses: softmax rows sum to 1 over the summed-out axis,
//  so the einsum output == x; only the projection+LN residual survives)
// EVERY loop fully unrolled: arrays must live in VGPRs (VGPR=40 last round proved
// they were in scratch), and unrolled straight-line code lets the compiler batch
// the uniform weight reads into s_load_dwordx16.
__global__ __launch_bounds__(256)
void k_embed(const float* __restrict__ X,
             const float* __restrict__ CW, const float* __restrict__ CB,
             const float* __restrict__ PW, const float* __restrict__ PB,
             const float* __restrict__ PG, const float* __restrict__ PBE,
             ushort_t* __restrict__ Hws)
{
    const int idx = blockIdx.x * 256 + threadIdx.x;   // 0..511999, grid exact
    const int b = idx / 1000, s = idx - b * 1000;

    const float2* xu = (const float2*)(X + (size_t)idx * 22);
    float xv[22];
#pragma unroll
    for (int j = 0; j < 11; ++j){
        float2 u = xu[j];
        xv[2*j] = u.x; xv[2*j+1] = u.y;
    }
    float v[16];
#pragma unroll
    for (int c = 0; c < 16; ++c){
        float a = CB[c];
#pragma unroll
        for (int j = 0; j < 22; ++j) a += xv[j] * CW[j*16 + c];
        v[c] = a;
    }
#pragma unroll
    for (int it = 0; it < 4; ++it){
        float u[16]; float m = 0.f;
#pragma unroll
        for (int c = 0; c < 16; ++c){
            float a = PB[c];
#pragma unroll
            for (int j = 0; j < 16; ++j) a += v[j] * PW[j*16 + c];
            u[c] = a; m += a;
        }
        m *= (1.f/16.f);
        float var = 0.f;
#pragma unroll
        for (int c = 0; c < 16; ++c){ float d = u[c] - m; var += d*d; }
        var *= (1.f/16.f);
        float inv = rsqrtf(var + 1e-5f);
#pragma unroll
        for (int c = 0; c < 16; ++c) v[c] += (u[c] - m) * inv * PG[c] + PBE[c];
    }
#pragma unroll
    for (int c = 0; c < 16; ++c)
        Hws[b*16000 + c*1000 + s] = f2u(v[c]);   // lanes -> consecutive s: coalesced
}

// ---------------- Kernel 2: conv1 -> BN -> LeakyReLU -> conv2 -> t (ws, f32) ------
__global__ __launch_bounds__(256)
void k_conv(const ushort_t* __restrict__ Hws,
            const float* __restrict__ W1, const float* __restrict__ B1,
            const float* __restrict__ BNG, const float* __restrict__ BNB,
            const float* __restrict__ BNM, const float* __restrict__ BNV,
            const float* __restrict__ W2, const float* __restrict__ B2,
            float* __restrict__ Tws)
{
    __shared__ __align__(16) float sH[16000];   // h[16][1000] f32

    const int tid = threadIdx.x;
    const int b   = blockIdx.x;

    for (int i = tid; i < 16000; i += 256) sH[i] = u2f(Hws[b*16000 + i]);

    // BN fold (uniform scalars)
    float sc[2], sh[2];
#pragma unroll
    for (int i = 0; i < 2; ++i){
        float s0 = BNG[i] * rsqrtf(BNV[i] + 1e-5f);
        sc[i] = s0;
        sh[i] = BNB[i] + (B1[i] - BNM[i]) * s0;
    }
    __syncthreads();

    if (tid < 190){
        const int w = tid;
        float acc[10];
#pragma unroll
        for (int o = 0; o < 10; ++o) acc[o] = B2[o];
        for (int kh = 0; kh < 16; ++kh){
            float hh[55];
#pragma unroll
            for (int j = 0; j < 55; ++j) hh[j] = sH[kh*1000 + 5*w + j];
            float val[2][5];
#pragma unroll
            for (int i = 0; i < 2; ++i){
#pragma unroll
                for (int kw = 0; kw < 5; ++kw){
                    float s = 0.f;
#pragma unroll
                    for (int k = 0; k < 51; ++k) s += hh[kw + k] * W1[i*51 + k];
                    s = s * sc[i] + sh[i];
                    val[i][kw] = s > 0.f ? s : 0.2f * s;
                }
            }
#pragma unroll
            for (int o = 0; o < 10; ++o){
                float s = acc[o];
#pragma unroll
                for (int i = 0; i < 2; ++i)
#pragma unroll
                    for (int kw = 0; kw < 5; ++kw)
                        s += val[i][kw] * W2[((o*2 + i)*16 + kh)*5 + kw];
                acc[o] = s;
            }
        }
#pragma unroll
        for (int o = 0; o < 10; ++o) Tws[(size_t)b*1900 + w*10 + o] = acc[o];
    }
}

// ---------------- Kernel 3: 3 transformer encoder layers (n=190, e=10, 5 heads) ---
// LDS: T (stride 11) + Q/K/V/AT (stride 12 -> aligned float2 pairs per head).
// Attention head-major: thread = (head, 4 queries) sharing one K/V float2 stream.
__global__ __launch_bounds__(256)
void k_tf(const float* __restrict__ Tws,
          const float* __restrict__ LN1G, const float* __restrict__ LN1B,
          const float* __restrict__ QW, const float* __restrict__ QBv,
          const float* __restrict__ KW, const float* __restrict__ KBv,
          const float* __restrict__ VW, const float* __restrict__ VBv,
          const float* __restrict__ OW, const float* __restrict__ OBv,
          const float* __restrict__ LN2G, const float* __restrict__ LN2B,
          const float* __restrict__ F1W, const float* __restrict__ F1B,
          const float* __restrict__ F2W, const float* __restrict__ F2B,
          float* __restrict__ OUT)
{
    __shared__ __align__(16) float T [190*11];
    __shared__ __align__(16) float QB[190*12];
    __shared__ __align__(16) float KB[190*12];
    __shared__ __align__(16) float VB[190*12];
    __shared__ __align__(16) float AT[190*12];

    const int tid = threadIdx.x;
    const int b   = blockIdx.x;

    for (int i = tid; i < 1900; i += 256){
        int r = i / 10, c = i - r*10;
        T[r*11 + c] = Tws[(size_t)b*1900 + i];
    }
    __syncthreads();

    const float SCALE = 0.31622776601683794f;   // 1/sqrt(10)
    const bool act = (tid < 190);
#pragma unroll 1
    for (int L = 0; L < 3; ++L){
        const float* ln1g = LN1G + L*10; const float* ln1b = LN1B + L*10;
        const float* qw = QW + L*100;    const float* qb = QBv + L*10;
        const float* kw = KW + L*100;    const float* kb = KBv + L*10;
        const float* vw = VW + L*100;    const float* vb = VBv + L*10;
        const float* ow = OW + L*100;    const float* ob = OBv + L*10;
        const float* ln2g = LN2G + L*10; const float* ln2b = LN2B + L*10;
        const float* f1w = F1W + L*400;  const float* f1b = F1B + L*40;
        const float* f2w = F2W + L*400;  const float* f2b = F2B + L*10;

        // ---- phase 1: LN1 + Q/K/V projections (190 threads) ----
        if (act){
            float tv[10], y[10];
#pragma unroll
            for (int c = 0; c < 10; ++c) tv[c] = T[tid*11 + c];
            ln10(tv, y, ln1g, ln1b);
#pragma unroll
            for (int c = 0; c < 10; ++c){
                float aq = qb[c], ak = kb[c], av = vb[c];
#pragma unroll
                for (int j = 0; j < 10; ++j){
                    aq += y[j] * qw[j*10 + c];
                    ak += y[j] * kw[j*10 + c];
                    av += y[j] * vw[j*10 + c];
                }
                QB[tid*12 + c] = aq;
                KB[tid*12 + c] = ak;
                VB[tid*12 + c] = av;
            }
        }
        __syncthreads();

        // ---- phase 2: attention, head-major (240 threads: head = tid/48) ----
        // no-max softmax: logits are O(1); jax's max-shift is mathematically identity.
        if (tid < 240){
            const int h5 = tid / 48;
            const int qg = tid - h5*48;      // 0..47
            const int q0 = qg * 4;           // 4 queries per thread
            float qx[4], qy[4];
#pragma unroll
            for (int i = 0; i < 4; ++i){
                int qi = q0 + i;
                if (qi < 190){
                    qx[i] = QB[qi*12 + 2*h5]     * SCALE;
                    qy[i] = QB[qi*12 + 2*h5 + 1] * SCALE;
                } else { qx[i] = 0.f; qy[i] = 0.f; }
            }
            float l[4] = {0,0,0,0}, a0[4] = {0,0,0,0}, a1[4] = {0,0,0,0};
#pragma unroll 2
            for (int kk = 0; kk < 190; ++kk){
                float2 kv = *(const float2*)&KB[kk*12 + 2*h5];
                float2 vv = *(const float2*)&VB[kk*12 + 2*h5];
#pragma unroll
                for (int i = 0; i < 4; ++i){
                    float p = __expf(qx[i]*kv.x + qy[i]*kv.y);
                    l[i] += p; a0[i] += p*vv.x; a1[i] += p*vv.y;
                }
            }
#pragma unroll
            for (int i = 0; i < 4; ++i){
                int qi = q0 + i;
                if (qi < 190){
                    float rl = 1.f / l[i];
                    AT[qi*12 + 2*h5]     = a0[i] * rl;
                    AT[qi*12 + 2*h5 + 1] = a1[i] * rl;
                }
            }
        }
        __syncthreads();

        // ---- phase 3: out-proj + residual + LN2 + FF(GELU) + residual ----
        if (act){
            float tv[10], at[10];
#pragma unroll
            for (int c = 0; c < 10; ++c){ tv[c] = T[tid*11 + c]; at[c] = AT[tid*12 + c]; }
#pragma unroll
            for (int c = 0; c < 10; ++c){
                float a = ob[c];
#pragma unroll
                for (int j = 0; j < 10; ++j) a += at[j] * ow[j*10 + c];
                tv[c] += a;
            }
            float y2[10];
            ln10(tv, y2, ln2g, ln2b);
            float g40[40];
#pragma unroll
            for (int j = 0; j < 40; ++j){
                float a = f1b[j];
#pragma unroll
                for (int c = 0; c < 10; ++c) a += y2[c] * f1w[c*40 + j];
                g40[j] = 0.5f * a * (1.f + erff(a * 0.70710678118654752f));  // exact GELU
            }
#pragma unroll
            for (int c = 0; c < 10; ++c){
                float a = f2b[c];
#pragma unroll
                for (int j = 0; j < 40; ++j) a += g40[j] * f2w[j*10 + c];
                tv[c] += a;
            }
#pragma unroll
            for (int c = 0; c < 10; ++c) T[tid*11 + c] = tv[c];
        }
        __syncthreads();
    }

    if (act){
#pragma unroll
        for (int c = 0; c < 10; ++c)
            OUT[(size_t)b*1900 + tid*10 + c] = T[tid*11 + c];
    }
}

extern "C" void kernel_launch(void* const* d_in, const int* in_sizes, int n_in,
                              void* d_out, int out_size, void* d_ws, size_t ws_size,
                              hipStream_t stream)
{
    (void)ws_size; (void)n_in; (void)out_size;
    const int B = in_sizes[0] / 22000;   // 512
    auto in = [&](int i){ return (const float*)d_in[i]; };
    ushort_t* Hws = (ushort_t*)d_ws;                              // B*16000 bf16 = 16.38 MB
    float*    Tws = (float*)((char*)d_ws + (size_t)B*16000*2);    // B*1900 f32  =  3.89 MB

    k_embed<<<(B*1000 + 255)/256, 256, 0, stream>>>(
        in(0), in(1), in(2), in(11), in(12), in(13), in(14), Hws);

    k_conv<<<B, 256, 0, stream>>>(
        Hws, in(15), in(16), in(17), in(18), in(19), in(20), in(21), in(22), Tws);

    k_tf<<<B, 256, 0, stream>>>(
        Tws,
        in(23), in(24), in(25), in(26), in(27), in(28), in(29), in(30),
        in(31), in(32), in(33), in(34), in(35), in(36), in(37), in(38),
        (float*)d_out);
}